// Round 11
// baseline (202.708 us; speedup 1.0000x reference)
//
#include <hip/hip_runtime.h>
#include <math.h>

// Algebraic refactor (verified rounds 1-10, absmax <= 0.0039):
//  y[0]=x[...,0]; y[k]=x[...,k]+relu(Wc@y[k-1])
//  z[0]=f(y[0]);  z[k]=f(y[k])+relu(Wc@z[k-1]),  f(v)=relu(v*inv+add)
//  S[col][dh] = sum_{o,k} A[dh][24-k][o] * t2[k][o][col],  t2[k]=f(z[k])
//  tail: lerp chains + sigmoid (k34)
// Round 11: PROBE ROUND. Real pipeline unchanged (R10). Two probe kernels
//  appended (write only ws scrap): p<1,4> = 4x serial loop on zeroed LDS
//  (loop cost isolated); p<0,4> = same without per-step barriers (upper
//  bound of barrier-free restructuring). Decides next structural move.

#define NC 8

typedef __attribute__((ext_vector_type(8))) short bf16x8;
typedef __attribute__((ext_vector_type(4))) float f32x4;

__device__ __forceinline__ float relu_(float v) { return fmaxf(v, 0.f); }

__device__ __forceinline__ short f2bf(float f) {
  union { float f; unsigned u; } v; v.f = f;
  unsigned r = (v.u + 0x7fffu + ((v.u >> 16) & 1u)) >> 16;
  return (short)r;
}
__device__ __forceinline__ float bf2f(short s) {
  union { unsigned u; float f; } v;
  v.u = ((unsigned)(unsigned short)s) << 16;
  return v.f;
}
__device__ __forceinline__ unsigned cvtpk(float lo, float hi) {
  unsigned r;
  asm("v_cvt_pk_bf16_f32 %0, %1, %2" : "=v"(r) : "v"(lo), "v"(hi));
  return r;
}
// lane^8 exchange within each 16-lane row: DPP row_ror:8 (VALU pipe, no DS)
__device__ __forceinline__ float dpp_xor8(float v) {
  int r = __builtin_amdgcn_update_dpp(0, __float_as_int(v), 0x128, 0xf, 0xf, true);
  return __int_as_float(r);
}

__global__ __launch_bounds__(64) void k0_precompute(
    const float* __restrict__ Wmsg, const float* __restrict__ gamma,
    const float* __restrict__ beta, const float* __restrict__ mean,
    const float* __restrict__ var, const float* __restrict__ Wup2,
    const float* __restrict__ Wconv, const float* __restrict__ Wconv2,
    short* __restrict__ WcA, float* __restrict__ A, float* __restrict__ bnp)
{
  const int c = blockIdx.x;      // 0..255
  const int lane = threadIdx.x;  // 0..63

  for (int o = lane; o < 256; o += 64)
    WcA[o * 256 + c] = f2bf(Wmsg[(o * 256 + c) * 9 + 4]);

  const int gtid = c * 64 + lane;
  if (gtid < 256) {
    float inv = gamma[gtid] / sqrtf(var[gtid] + 1e-5f);
    bnp[gtid] = inv;
    bnp[256 + gtid] = beta[gtid] - mean[gtid] * inv;
  }

  float wacc[9];
#pragma unroll
  for (int q = 0; q < 9; ++q) wacc[q] = 0.f;
  for (int o = lane; o < 256; o += 64) {
    float cw = Wconv[o];
    const float* wp = Wup2 + (size_t)(o * 256 + c) * 9;
#pragma unroll
    for (int q = 0; q < 9; ++q) wacc[q] += cw * wp[q];
  }
#pragma unroll
  for (int q = 0; q < 9; ++q) {
    float v = wacc[q];
    v += __shfl_xor(v, 32, 64);
    v += __shfl_xor(v, 16, 64);
    v += __shfl_xor(v, 8, 64);
    v += __shfl_xor(v, 4, 64);
    v += __shfl_xor(v, 2, 64);
    v += __shfl_xor(v, 1, 64);
    wacc[q] = v;
  }
  if (lane == 0) {
    for (int dh = 0; dh < 3; ++dh)
      for (int j = 0; j < 25; ++j) {
        float a = 0.f;
        for (int dw = 0; dw < 3; ++dw) {
          int w = j + 1 - dw;
          if (w >= 0 && w < 25) a += wacc[dh * 3 + dw] * Wconv2[w];
        }
        A[(dh * 25 + j) * 256 + c] = a;
      }
  }
}

// ---- fused MFMA dual-recurrence kernel (8 waves x 32 channels, NC=8) ----
__global__ __launch_bounds__(512, 1) void k2_fused(
    const float* __restrict__ X,     // p2_r [b][c][h][w]
    const short* __restrict__ WcA,   // bf16 [o][c]
    const float* __restrict__ A,     // [(dh*25+w)*256+c]
    const float* __restrict__ bnp,   // inv[256], add[256]
    float* __restrict__ S)           // [col*3+dh]
{
  __shared__ short xslab[25 * 8 * 256];  // 102400B
  __shared__ short yz[2][16 * 256];      // state, swizzled (2x8192B)
  __shared__ float red[8][8][3];
  const int tid = threadIdx.x;
  const int wave = tid >> 6;
  const int lane = tid & 63;
  const int n = lane & 15;
  const int nr = n & 7;
  const int g = lane >> 4;
  const bool isz = (n >= 8);
  const int col0 = blockIdx.x * NC;      // col = b*256+h
  const int b = col0 >> 8, h0 = col0 & 255;
  const int obase = wave * 32;
  char* xs = (char*)xslab;
  char* smem = (char*)yz;

  if (lane < 50) {
    int base_[4], sx_[4];
#pragma unroll
    for (int e = 0; e < 4; ++e) {
      int f = 4 * lane + e;
      int rn = f / 25, w = f - rn * 25;
      base_[e] = w * 4096 + rn * 512;
      sx_[e] = ((2 * rn + w) & 15) << 3;
    }
    const float* src0 = X + (size_t)(b * 256 + obase) * 6400 + h0 * 25 + 4 * lane;
#pragma unroll 4
    for (int i = 0; i < 16; ++i) {
      float4 v0 = *(const float4*)(src0 + (size_t)(2 * i) * 6400);
      float4 v1 = *(const float4*)(src0 + (size_t)(2 * i + 1) * 6400);
      unsigned p[4] = {cvtpk(v0.x, v1.x), cvtpk(v0.y, v1.y),
                       cvtpk(v0.z, v1.z), cvtpk(v0.w, v1.w)};
      const int cb = 2 * obase + 4 * i;
#pragma unroll
      for (int e = 0; e < 4; ++e)
        *(unsigned*)(xs + base_[e] + (cb ^ sx_[e])) = p[e];
    }
  }

  f32x4 inv[2], addv[2];
#pragma unroll
  for (int t = 0; t < 2; ++t) {
    inv[t] = *(const f32x4*)(bnp + obase + t * 16 + g * 4);
    addv[t] = *(const f32x4*)(bnp + 256 + obase + t * 16 + g * 4);
  }

  bf16x8 af[2][8];
#pragma unroll
  for (int t = 0; t < 2; ++t)
#pragma unroll
    for (int kk = 0; kk < 8; ++kk)
      af[t][kk] = *(const bf16x8*)(WcA + (obase + t * 16 + n) * 256 + kk * 32 + g * 8);

  const int swz = nr << 4;
  int woff[2], xb[2], roff[8];
#pragma unroll
  for (int t = 0; t < 2; ++t) {
    woff[t] = n * 512 + (((obase + t * 16 + g * 4) * 2) ^ swz);
    xb[t] = nr * 512 + 2 * (obase + t * 16 + g * 4);
  }
#pragma unroll
  for (int kk = 0; kk < 8; ++kk)
    roff[kk] = n * 512 + ((kk * 64 + g * 16) ^ swz);

  __syncthreads();  // slab ready

  {
    const int S0 = ((2 * nr) & 15) << 3;
#pragma unroll
    for (int t = 0; t < 2; ++t) {
      uint2 xq0 = *(const uint2*)(xs + (xb[t] ^ S0));
      if (!isz) {
        *(uint2*)(smem + woff[t]) = xq0;
      } else {
        float zr[4], t2r[4];
        float xv[4] = {bf2f((short)xq0.x), bf2f((short)(xq0.x >> 16)),
                       bf2f((short)xq0.y), bf2f((short)(xq0.y >> 16))};
#pragma unroll
        for (int r = 0; r < 4; ++r) {
          zr[r] = relu_(xv[r] * inv[t][r] + addv[t][r]);
          t2r[r] = relu_(zr[r] * inv[t][r] + addv[t][r]);
        }
        *(uint2*)(smem + woff[t]) = make_uint2(cvtpk(zr[0], zr[1]), cvtpk(zr[2], zr[3]));
        *(uint2*)(xs + (xb[t] ^ S0)) =
            make_uint2(cvtpk(t2r[0], t2r[1]), cvtpk(t2r[2], t2r[3]));
      }
    }
  }

  uint2 xq[2];
  xq[0] = make_uint2(0u, 0u);
  xq[1] = make_uint2(0u, 0u);
  if (!isz) {
    const int S1 = ((2 * nr + 1) & 15) << 3;
#pragma unroll
    for (int t = 0; t < 2; ++t)
      xq[t] = *(const uint2*)(xs + ((xb[t] + 4096) ^ S1));
  }
  __syncthreads();

#pragma unroll 1
  for (int k = 1; k < 25; ++k) {
    const int cur = (k - 1) & 1, nxt = k & 1;

    bf16x8 bfr[8];
#pragma unroll
    for (int kk = 0; kk < 8; ++kk)
      bfr[kk] = *(const bf16x8*)(smem + cur * 8192 + roff[kk]);

    f32x4 accA[2], accB[2];
#pragma unroll
    for (int t = 0; t < 2; ++t) {
      accA[t] = (f32x4){0.f, 0.f, 0.f, 0.f};
      accB[t] = (f32x4){0.f, 0.f, 0.f, 0.f};
    }
    __builtin_amdgcn_s_setprio(1);
#pragma unroll
    for (int kk = 0; kk < 4; ++kk)
#pragma unroll
      for (int t = 0; t < 2; ++t)
        accA[t] = __builtin_amdgcn_mfma_f32_16x16x32_bf16(af[t][kk], bfr[kk], accA[t], 0, 0, 0);
#pragma unroll
    for (int kk = 4; kk < 8; ++kk)
#pragma unroll
      for (int t = 0; t < 2; ++t)
        accB[t] = __builtin_amdgcn_mfma_f32_16x16x32_bf16(af[t][kk], bfr[kk], accB[t], 0, 0, 0);
    __builtin_amdgcn_s_setprio(0);

    float cyv[2][4], ynv[2][4], t1v[2][4], t1s[2][4];
#pragma unroll
    for (int t = 0; t < 2; ++t) {
      f32x4 acc = accA[t] + accB[t];
      float xv[4];
      xv[0] = bf2f((short)xq[t].x);
      xv[1] = bf2f((short)(xq[t].x >> 16));
      xv[2] = bf2f((short)xq[t].y);
      xv[3] = bf2f((short)(xq[t].y >> 16));
#pragma unroll
      for (int r = 0; r < 4; ++r) {
        cyv[t][r] = relu_(acc[r]);
        ynv[t][r] = xv[r] + cyv[t][r];
        t1v[t][r] = relu_(ynv[t][r] * inv[t][r] + addv[t][r]);
      }
    }
#pragma unroll
    for (int t = 0; t < 2; ++t)
#pragma unroll
      for (int r = 0; r < 4; ++r) t1s[t][r] = dpp_xor8(t1v[t][r]);
#pragma unroll
    for (int t = 0; t < 2; ++t) {
      float sel[4], tt2[4];
#pragma unroll
      for (int r = 0; r < 4; ++r) {
        float znew = t1s[t][r] + cyv[t][r];
        tt2[r] = relu_(znew * inv[t][r] + addv[t][r]);
        sel[r] = isz ? znew : ynv[t][r];
      }
      *(uint2*)(smem + nxt * 8192 + woff[t]) =
          make_uint2(cvtpk(sel[0], sel[1]), cvtpk(sel[2], sel[3]));
      if (isz)
        *(uint2*)(xs + ((xb[t] + k * 4096) ^ (((2 * nr + k) & 15) << 3))) =
            make_uint2(cvtpk(tt2[0], tt2[1]), cvtpk(tt2[2], tt2[3]));
    }

    if (k < 24 && !isz) {
      const int Sn = ((2 * nr + k + 1) & 15) << 3;
#pragma unroll
      for (int t = 0; t < 2; ++t)
        xq[t] = *(const uint2*)(xs + ((xb[t] + (k + 1) * 4096) ^ Sn));
    }
    __syncthreads();
  }

  {
    const int kb = (wave == 0) ? 0 : 4 + 3 * (wave - 1);
    const int ke = kb + (wave ? 3 : 4);
    float acc[8][3];
#pragma unroll
    for (int rn = 0; rn < 8; ++rn)
#pragma unroll
      for (int dh = 0; dh < 3; ++dh) acc[rn][dh] = 0.f;

#pragma unroll 1
    for (int k = kb; k < ke; ++k) {
      f32x4 a0 = *(const f32x4*)(A + (0 * 25 + 24 - k) * 256 + 4 * lane);
      f32x4 a1 = *(const f32x4*)(A + (1 * 25 + 24 - k) * 256 + 4 * lane);
      f32x4 a2 = *(const f32x4*)(A + (2 * 25 + 24 - k) * 256 + 4 * lane);
#pragma unroll
      for (int rn = 0; rn < 8; ++rn) {
        int Sp = ((2 * rn + k) & 15) << 3;
        uint2 q = *(const uint2*)(xs + ((k * 4096 + rn * 512 + 8 * lane) ^ Sp));
        float v0 = bf2f((short)q.x), v1 = bf2f((short)(q.x >> 16));
        float v2 = bf2f((short)q.y), v3 = bf2f((short)(q.y >> 16));
#pragma unroll
        for (int dh = 0; dh < 3; ++dh) {
          f32x4 a = dh == 0 ? a0 : (dh == 1 ? a1 : a2);
          float s = acc[rn][dh];
          s = fmaf(a[0], v0, s);
          s = fmaf(a[1], v1, s);
          s = fmaf(a[2], v2, s);
          s = fmaf(a[3], v3, s);
          acc[rn][dh] = s;
        }
      }
    }
#pragma unroll
    for (int rn = 0; rn < 8; ++rn)
#pragma unroll
      for (int dh = 0; dh < 3; ++dh) {
        float v = acc[rn][dh];
        v += __shfl_xor(v, 1);
        v += __shfl_xor(v, 2);
        v += __shfl_xor(v, 4);
        v += __shfl_xor(v, 8);
        v += __shfl_xor(v, 16);
        v += __shfl_xor(v, 32);
        if (lane == 0) red[wave][rn][dh] = v;
      }
  }
  __syncthreads();
  if (tid < 24) {
    int nn = tid / 3, dh = tid % 3;
    float v = 0.f;
#pragma unroll
    for (int ww = 0; ww < 8; ++ww) v += red[ww][nn][dh];
    S[(size_t)(col0 + nn) * 3 + dh] = v;
  }
}

// ---- PROBE: serial loop on zeroed LDS, REP repeats, optional barriers ----
// Writes only scrap (ws). Timing instrument; removed once decisive.
template <int BAR, int REP>
__global__ __launch_bounds__(512, 1) void k2_probe(
    const short* __restrict__ WcA, const float* __restrict__ A,
    const float* __restrict__ bnp, float* __restrict__ scrap)
{
  __shared__ short xslab[25 * 8 * 256];
  __shared__ short yz[2][16 * 256];
  __shared__ float red[8][8][3];
  const int tid = threadIdx.x;
  const int wave = tid >> 6;
  const int lane = tid & 63;
  const int n = lane & 15;
  const int nr = n & 7;
  const int g = lane >> 4;
  const bool isz = (n >= 8);
  const int obase = wave * 32;
  char* xs = (char*)xslab;
  char* smem = (char*)yz;

  // zero-init LDS (replaces staging)
  {
    unsigned* xw = (unsigned*)xslab;
    for (int i = tid; i < 25600; i += 512) xw[i] = 0u;
    unsigned* yw = (unsigned*)yz;
    for (int i = tid; i < 4096; i += 512) yw[i] = 0u;
  }

  f32x4 inv[2], addv[2];
#pragma unroll
  for (int t = 0; t < 2; ++t) {
    inv[t] = *(const f32x4*)(bnp + obase + t * 16 + g * 4);
    addv[t] = *(const f32x4*)(bnp + 256 + obase + t * 16 + g * 4);
  }
  bf16x8 af[2][8];
#pragma unroll
  for (int t = 0; t < 2; ++t)
#pragma unroll
    for (int kk = 0; kk < 8; ++kk)
      af[t][kk] = *(const bf16x8*)(WcA + (obase + t * 16 + n) * 256 + kk * 32 + g * 8);

  const int swz = nr << 4;
  int woff[2], xb[2], roff[8];
#pragma unroll
  for (int t = 0; t < 2; ++t) {
    woff[t] = n * 512 + (((obase + t * 16 + g * 4) * 2) ^ swz);
    xb[t] = nr * 512 + 2 * (obase + t * 16 + g * 4);
  }
#pragma unroll
  for (int kk = 0; kk < 8; ++kk)
    roff[kk] = n * 512 + ((kk * 64 + g * 16) ^ swz);

  __syncthreads();

  uint2 xq[2];
  xq[0] = make_uint2(0u, 0u);
  xq[1] = make_uint2(0u, 0u);
  if (!isz) {
    const int S1 = ((2 * nr + 1) & 15) << 3;
#pragma unroll
    for (int t = 0; t < 2; ++t)
      xq[t] = *(const uint2*)(xs + ((xb[t] + 4096) ^ S1));
  }
  __syncthreads();

#pragma unroll 1
  for (int rep = 0; rep < REP; ++rep) {
#pragma unroll 1
    for (int k = 1; k < 25; ++k) {
      const int cur = (k - 1) & 1, nxt = k & 1;

      bf16x8 bfr[8];
#pragma unroll
      for (int kk = 0; kk < 8; ++kk)
        bfr[kk] = *(const bf16x8*)(smem + cur * 8192 + roff[kk]);

      f32x4 accA[2], accB[2];
#pragma unroll
      for (int t = 0; t < 2; ++t) {
        accA[t] = (f32x4){0.f, 0.f, 0.f, 0.f};
        accB[t] = (f32x4){0.f, 0.f, 0.f, 0.f};
      }
      __builtin_amdgcn_s_setprio(1);
#pragma unroll
      for (int kk = 0; kk < 4; ++kk)
#pragma unroll
        for (int t = 0; t < 2; ++t)
          accA[t] = __builtin_amdgcn_mfma_f32_16x16x32_bf16(af[t][kk], bfr[kk], accA[t], 0, 0, 0);
#pragma unroll
      for (int kk = 4; kk < 8; ++kk)
#pragma unroll
        for (int t = 0; t < 2; ++t)
          accB[t] = __builtin_amdgcn_mfma_f32_16x16x32_bf16(af[t][kk], bfr[kk], accB[t], 0, 0, 0);
      __builtin_amdgcn_s_setprio(0);

      float cyv[2][4], ynv[2][4], t1v[2][4], t1s[2][4];
#pragma unroll
      for (int t = 0; t < 2; ++t) {
        f32x4 acc = accA[t] + accB[t];
        float xv[4];
        xv[0] = bf2f((short)xq[t].x);
        xv[1] = bf2f((short)(xq[t].x >> 16));
        xv[2] = bf2f((short)xq[t].y);
        xv[3] = bf2f((short)(xq[t].y >> 16));
#pragma unroll
        for (int r = 0; r < 4; ++r) {
          cyv[t][r] = relu_(acc[r]);
          ynv[t][r] = xv[r] + cyv[t][r];
          t1v[t][r] = relu_(ynv[t][r] * inv[t][r] + addv[t][r]);
        }
      }
#pragma unroll
      for (int t = 0; t < 2; ++t)
#pragma unroll
        for (int r = 0; r < 4; ++r) t1s[t][r] = dpp_xor8(t1v[t][r]);
#pragma unroll
      for (int t = 0; t < 2; ++t) {
        float sel[4], tt2[4];
#pragma unroll
        for (int r = 0; r < 4; ++r) {
          float znew = t1s[t][r] + cyv[t][r];
          tt2[r] = relu_(znew * inv[t][r] + addv[t][r]);
          sel[r] = isz ? znew : ynv[t][r];
        }
        *(uint2*)(smem + nxt * 8192 + woff[t]) =
            make_uint2(cvtpk(sel[0], sel[1]), cvtpk(sel[2], sel[3]));
        if (isz)
          *(uint2*)(xs + ((xb[t] + k * 4096) ^ (((2 * nr + k) & 15) << 3))) =
              make_uint2(cvtpk(tt2[0], tt2[1]), cvtpk(tt2[2], tt2[3]));
      }

      if (k < 24 && !isz) {
        const int Sn = ((2 * nr + k + 1) & 15) << 3;
#pragma unroll
        for (int t = 0; t < 2; ++t)
          xq[t] = *(const uint2*)(xs + ((xb[t] + (k + 1) * 4096) ^ Sn));
      }
      if constexpr (BAR) __syncthreads();
    }
  }
  __syncthreads();

  // post-phase (consumes xslab; writes scrap)
  {
    const int kb = (wave == 0) ? 0 : 4 + 3 * (wave - 1);
    const int ke = kb + (wave ? 3 : 4);
    float acc[8][3];
#pragma unroll
    for (int rn = 0; rn < 8; ++rn)
#pragma unroll
      for (int dh = 0; dh < 3; ++dh) acc[rn][dh] = 0.f;
#pragma unroll 1
    for (int k = kb; k < ke; ++k) {
      f32x4 a0 = *(const f32x4*)(A + (0 * 25 + 24 - k) * 256 + 4 * lane);
      f32x4 a1 = *(const f32x4*)(A + (1 * 25 + 24 - k) * 256 + 4 * lane);
      f32x4 a2 = *(const f32x4*)(A + (2 * 25 + 24 - k) * 256 + 4 * lane);
#pragma unroll
      for (int rn = 0; rn < 8; ++rn) {
        int Sp = ((2 * rn + k) & 15) << 3;
        uint2 q = *(const uint2*)(xs + ((k * 4096 + rn * 512 + 8 * lane) ^ Sp));
        float v0 = bf2f((short)q.x), v1 = bf2f((short)(q.x >> 16));
        float v2 = bf2f((short)q.y), v3 = bf2f((short)(q.y >> 16));
#pragma unroll
        for (int dh = 0; dh < 3; ++dh) {
          f32x4 a = dh == 0 ? a0 : (dh == 1 ? a1 : a2);
          float s = acc[rn][dh];
          s = fmaf(a[0], v0, s);
          s = fmaf(a[1], v1, s);
          s = fmaf(a[2], v2, s);
          s = fmaf(a[3], v3, s);
          acc[rn][dh] = s;
        }
      }
    }
#pragma unroll
    for (int rn = 0; rn < 8; ++rn)
#pragma unroll
      for (int dh = 0; dh < 3; ++dh) {
        float v = acc[rn][dh];
        v += __shfl_xor(v, 1);
        v += __shfl_xor(v, 2);
        v += __shfl_xor(v, 4);
        v += __shfl_xor(v, 8);
        v += __shfl_xor(v, 16);
        v += __shfl_xor(v, 32);
        if (lane == 0) red[wave][rn][dh] = v;
      }
  }
  __syncthreads();
  if (tid < 24) {
    int nn = tid / 3, dh = tid % 3;
    float v = 0.f;
#pragma unroll
    for (int ww = 0; ww < 8; ++ww) v += red[ww][nn][dh];
    scrap[(size_t)(blockIdx.x * NC + nn) * 3 + dh] = v;
  }
}

// ---- merged tail: conv-h fold + 3 upsamples + sigmoid ----
__global__ __launch_bounds__(256) void k34_final(
    const float* __restrict__ S, float* __restrict__ out)
{
  int idx = blockIdx.x * blockDim.x + threadIdx.x;
  if (idx >= 8 * 2048) return;
  int b = idx >> 11, H = idx & 2047;

  auto Pf = [&](int h) -> float {
    float acc = 0.f;
#pragma unroll
    for (int dh = 0; dh < 3; ++dh) {
      int hh = h + dh - 1;
      if (hh < 0 || hh >= 512) continue;
      float pos = hh * (255.0f / 511.0f);
      int i0 = (int)floorf(pos);
      int i1 = min(i0 + 1, 255);
      float t = pos - (float)i0;
      acc += (1.f - t) * S[(size_t)(b * 256 + i0) * 3 + dh]
           + t * S[(size_t)(b * 256 + i1) * 3 + dh];
    }
    return acc;
  };

  float pos3 = H * (1023.0f / 2047.0f);
  int i3 = (int)floorf(pos3);
  int i3b = min(i3 + 1, 1023);
  float t3 = pos3 - (float)i3;

  float v[2];
#pragma unroll
  for (int q = 0; q < 2; ++q) {
    int i = q ? i3b : i3;
    float pos2 = i * (511.0f / 1023.0f);
    int i2 = (int)floorf(pos2);
    int i2b = min(i2 + 1, 511);
    float t2 = pos2 - (float)i2;
    v[q] = (1.f - t2) * Pf(i2) + t2 * Pf(i2b);
  }
  float val = (1.f - t3) * v[0] + t3 * v[1];
  out[idx] = 1.f / (1.f + expf(-val));
}

extern "C" void kernel_launch(void* const* d_in, const int* in_sizes, int n_in,
                              void* d_out, int out_size, void* d_ws, size_t ws_size,
                              hipStream_t stream) {
  (void)in_sizes; (void)n_in; (void)out_size; (void)ws_size;
  const float* p2r    = (const float*)d_in[0];
  const float* Wmsg   = (const float*)d_in[1];
  const float* gamma  = (const float*)d_in[2];
  const float* beta   = (const float*)d_in[3];
  const float* mean   = (const float*)d_in[4];
  const float* var    = (const float*)d_in[5];
  const float* Wup2   = (const float*)d_in[6];
  const float* Wconv  = (const float*)d_in[7];
  const float* Wconv2 = (const float*)d_in[8];
  float* out = (float*)d_out;

  float* ws = (float*)d_ws;
  size_t off = 0;
  short* WcA = (short*)(ws + off); off += 32768;  // 65536 bf16
  float* Abuf = ws + off; off += 19200;
  float* bnp = ws + off;  off += 512;
  float* S = ws + off;    off += 6144;
  float* scrap = ws + off; off += 6144;

  k0_precompute<<<256, 64, 0, stream>>>(Wmsg, gamma, beta, mean, var, Wup2,
                                        Wconv, Wconv2, WcA, Abuf, bnp);
  k2_fused<<<256, 512, 0, stream>>>(p2r, (const short*)WcA, Abuf, bnp, S);
  k34_final<<<64, 256, 0, stream>>>(S, out);
  // probes (timing instruments; write only scrap)
  k2_probe<1, 4><<<256, 512, 0, stream>>>((const short*)WcA, Abuf, bnp, scrap);
  k2_probe<0, 4><<<256, 512, 0, stream>>>((const short*)WcA, Abuf, bnp, scrap);
}

// Round 12
// 71.969 us; speedup vs baseline: 2.8166x; 2.8166x over previous
//
#include <hip/hip_runtime.h>
#include <math.h>

// Algebraic refactor (verified rounds 1-11, absmax <= 0.0039):
//  y[0]=x[...,0]; y[k]=x[...,k]+relu(Wc@y[k-1])
//  z[0]=f(y[0]);  z[k]=f(y[k])+relu(Wc@z[k-1]),  f(v)=relu(v*inv+add)
//  S[col][dh] = sum_{o,k} A[dh][24-k][o] * t2[k][o][col],  t2[k]=f(z[k])
//  tail: lerp chains + sigmoid (k34)
// Round 12: probe verdicts: barriers FREE (p<0,4>==p<1,4>); loop = 23us;
//  non-loop = ~21us. Suspect: staging load->use interleave limits MLP to
//  ~2-4 inflight. Fix: batched 16-deep load issue, then pack+write.
//  A/B probes p_stage<0/1> isolate old vs new staging in the same run.

#define NC 8

typedef __attribute__((ext_vector_type(8))) short bf16x8;
typedef __attribute__((ext_vector_type(4))) float f32x4;

__device__ __forceinline__ float relu_(float v) { return fmaxf(v, 0.f); }

__device__ __forceinline__ short f2bf(float f) {
  union { float f; unsigned u; } v; v.f = f;
  unsigned r = (v.u + 0x7fffu + ((v.u >> 16) & 1u)) >> 16;
  return (short)r;
}
__device__ __forceinline__ float bf2f(short s) {
  union { unsigned u; float f; } v;
  v.u = ((unsigned)(unsigned short)s) << 16;
  return v.f;
}
__device__ __forceinline__ unsigned cvtpk(float lo, float hi) {
  unsigned r;
  asm("v_cvt_pk_bf16_f32 %0, %1, %2" : "=v"(r) : "v"(lo), "v"(hi));
  return r;
}
// lane^8 exchange within each 16-lane row: DPP row_ror:8 (VALU pipe, no DS)
__device__ __forceinline__ float dpp_xor8(float v) {
  int r = __builtin_amdgcn_update_dpp(0, __float_as_int(v), 0x128, 0xf, 0xf, true);
  return __int_as_float(r);
}

// ---- staging routine, two variants (VAR 0 = interleaved, 1 = batched) ----
template <int VAR>
__device__ __forceinline__ void stage_slab(
    const float* __restrict__ X, char* xs, int b, int h0, int obase, int lane)
{
  if (lane >= 50) return;
  int base_[4], sx_[4];
#pragma unroll
  for (int e = 0; e < 4; ++e) {
    int f = 4 * lane + e;
    int rn = f / 25, w = f - rn * 25;
    base_[e] = w * 4096 + rn * 512;
    sx_[e] = ((2 * rn + w) & 15) << 3;
  }
  const float* src0 = X + (size_t)(b * 256 + obase) * 6400 + h0 * 25 + 4 * lane;

  if constexpr (VAR == 0) {
    // old: load pair -> immediately pack+write (vmcnt drains each iter)
#pragma unroll 4
    for (int i = 0; i < 16; ++i) {
      float4 v0 = *(const float4*)(src0 + (size_t)(2 * i) * 6400);
      float4 v1 = *(const float4*)(src0 + (size_t)(2 * i + 1) * 6400);
      unsigned p[4] = {cvtpk(v0.x, v1.x), cvtpk(v0.y, v1.y),
                       cvtpk(v0.z, v1.z), cvtpk(v0.w, v1.w)};
      const int cb = 2 * obase + 4 * i;
#pragma unroll
      for (int e = 0; e < 4; ++e)
        *(unsigned*)(xs + base_[e] + (cb ^ sx_[e])) = p[e];
    }
  } else {
    // new: issue 16 loads back-to-back (MLP 16), then pack+write; 2 batches
#pragma unroll
    for (int hb = 0; hb < 2; ++hb) {
      float4 va[16];
#pragma unroll
      for (int j = 0; j < 16; ++j)
        va[j] = *(const float4*)(src0 + (size_t)(hb * 16 + j) * 6400);
#pragma unroll
      for (int i = 0; i < 8; ++i) {
        unsigned p[4] = {cvtpk(va[2 * i].x, va[2 * i + 1].x),
                         cvtpk(va[2 * i].y, va[2 * i + 1].y),
                         cvtpk(va[2 * i].z, va[2 * i + 1].z),
                         cvtpk(va[2 * i].w, va[2 * i + 1].w)};
        const int cb = 2 * obase + 4 * (hb * 8 + i);
#pragma unroll
        for (int e = 0; e < 4; ++e)
          *(unsigned*)(xs + base_[e] + (cb ^ sx_[e])) = p[e];
      }
    }
  }
}

__global__ __launch_bounds__(64) void k0_precompute(
    const float* __restrict__ Wmsg, const float* __restrict__ gamma,
    const float* __restrict__ beta, const float* __restrict__ mean,
    const float* __restrict__ var, const float* __restrict__ Wup2,
    const float* __restrict__ Wconv, const float* __restrict__ Wconv2,
    short* __restrict__ WcA, float* __restrict__ A, float* __restrict__ bnp)
{
  const int c = blockIdx.x;      // 0..255
  const int lane = threadIdx.x;  // 0..63

  for (int o = lane; o < 256; o += 64)
    WcA[o * 256 + c] = f2bf(Wmsg[(o * 256 + c) * 9 + 4]);

  const int gtid = c * 64 + lane;
  if (gtid < 256) {
    float inv = gamma[gtid] / sqrtf(var[gtid] + 1e-5f);
    bnp[gtid] = inv;
    bnp[256 + gtid] = beta[gtid] - mean[gtid] * inv;
  }

  float wacc[9];
#pragma unroll
  for (int q = 0; q < 9; ++q) wacc[q] = 0.f;
  for (int o = lane; o < 256; o += 64) {
    float cw = Wconv[o];
    const float* wp = Wup2 + (size_t)(o * 256 + c) * 9;
#pragma unroll
    for (int q = 0; q < 9; ++q) wacc[q] += cw * wp[q];
  }
#pragma unroll
  for (int q = 0; q < 9; ++q) {
    float v = wacc[q];
    v += __shfl_xor(v, 32, 64);
    v += __shfl_xor(v, 16, 64);
    v += __shfl_xor(v, 8, 64);
    v += __shfl_xor(v, 4, 64);
    v += __shfl_xor(v, 2, 64);
    v += __shfl_xor(v, 1, 64);
    wacc[q] = v;
  }
  if (lane == 0) {
    for (int dh = 0; dh < 3; ++dh)
      for (int j = 0; j < 25; ++j) {
        float a = 0.f;
        for (int dw = 0; dw < 3; ++dw) {
          int w = j + 1 - dw;
          if (w >= 0 && w < 25) a += wacc[dh * 3 + dw] * Wconv2[w];
        }
        A[(dh * 25 + j) * 256 + c] = a;
      }
  }
}

// ---- fused MFMA dual-recurrence kernel (8 waves x 32 channels, NC=8) ----
__global__ __launch_bounds__(512, 1) void k2_fused(
    const float* __restrict__ X,     // p2_r [b][c][h][w]
    const short* __restrict__ WcA,   // bf16 [o][c]
    const float* __restrict__ A,     // [(dh*25+w)*256+c]
    const float* __restrict__ bnp,   // inv[256], add[256]
    float* __restrict__ S)           // [col*3+dh]
{
  __shared__ short xslab[25 * 8 * 256];  // 102400B
  __shared__ short yz[2][16 * 256];      // state, swizzled (2x8192B)
  __shared__ float red[8][8][3];
  const int tid = threadIdx.x;
  const int wave = tid >> 6;
  const int lane = tid & 63;
  const int n = lane & 15;
  const int nr = n & 7;
  const int g = lane >> 4;
  const bool isz = (n >= 8);
  const int col0 = blockIdx.x * NC;      // col = b*256+h
  const int b = col0 >> 8, h0 = col0 & 255;
  const int obase = wave * 32;
  char* xs = (char*)xslab;
  char* smem = (char*)yz;

  stage_slab<1>(X, xs, b, h0, obase, lane);

  f32x4 inv[2], addv[2];
#pragma unroll
  for (int t = 0; t < 2; ++t) {
    inv[t] = *(const f32x4*)(bnp + obase + t * 16 + g * 4);
    addv[t] = *(const f32x4*)(bnp + 256 + obase + t * 16 + g * 4);
  }

  bf16x8 af[2][8];
#pragma unroll
  for (int t = 0; t < 2; ++t)
#pragma unroll
    for (int kk = 0; kk < 8; ++kk)
      af[t][kk] = *(const bf16x8*)(WcA + (obase + t * 16 + n) * 256 + kk * 32 + g * 8);

  const int swz = nr << 4;
  int woff[2], xb[2], roff[8];
#pragma unroll
  for (int t = 0; t < 2; ++t) {
    woff[t] = n * 512 + (((obase + t * 16 + g * 4) * 2) ^ swz);
    xb[t] = nr * 512 + 2 * (obase + t * 16 + g * 4);
  }
#pragma unroll
  for (int kk = 0; kk < 8; ++kk)
    roff[kk] = n * 512 + ((kk * 64 + g * 16) ^ swz);

  __syncthreads();  // slab ready

  {
    const int S0 = ((2 * nr) & 15) << 3;
#pragma unroll
    for (int t = 0; t < 2; ++t) {
      uint2 xq0 = *(const uint2*)(xs + (xb[t] ^ S0));
      if (!isz) {
        *(uint2*)(smem + woff[t]) = xq0;
      } else {
        float zr[4], t2r[4];
        float xv[4] = {bf2f((short)xq0.x), bf2f((short)(xq0.x >> 16)),
                       bf2f((short)xq0.y), bf2f((short)(xq0.y >> 16))};
#pragma unroll
        for (int r = 0; r < 4; ++r) {
          zr[r] = relu_(xv[r] * inv[t][r] + addv[t][r]);
          t2r[r] = relu_(zr[r] * inv[t][r] + addv[t][r]);
        }
        *(uint2*)(smem + woff[t]) = make_uint2(cvtpk(zr[0], zr[1]), cvtpk(zr[2], zr[3]));
        *(uint2*)(xs + (xb[t] ^ S0)) =
            make_uint2(cvtpk(t2r[0], t2r[1]), cvtpk(t2r[2], t2r[3]));
      }
    }
  }

  uint2 xq[2];
  xq[0] = make_uint2(0u, 0u);
  xq[1] = make_uint2(0u, 0u);
  if (!isz) {
    const int S1 = ((2 * nr + 1) & 15) << 3;
#pragma unroll
    for (int t = 0; t < 2; ++t)
      xq[t] = *(const uint2*)(xs + ((xb[t] + 4096) ^ S1));
  }
  __syncthreads();

#pragma unroll 1
  for (int k = 1; k < 25; ++k) {
    const int cur = (k - 1) & 1, nxt = k & 1;

    bf16x8 bfr[8];
#pragma unroll
    for (int kk = 0; kk < 8; ++kk)
      bfr[kk] = *(const bf16x8*)(smem + cur * 8192 + roff[kk]);

    f32x4 accA[2], accB[2];
#pragma unroll
    for (int t = 0; t < 2; ++t) {
      accA[t] = (f32x4){0.f, 0.f, 0.f, 0.f};
      accB[t] = (f32x4){0.f, 0.f, 0.f, 0.f};
    }
    __builtin_amdgcn_s_setprio(1);
#pragma unroll
    for (int kk = 0; kk < 4; ++kk)
#pragma unroll
      for (int t = 0; t < 2; ++t)
        accA[t] = __builtin_amdgcn_mfma_f32_16x16x32_bf16(af[t][kk], bfr[kk], accA[t], 0, 0, 0);
#pragma unroll
    for (int kk = 4; kk < 8; ++kk)
#pragma unroll
      for (int t = 0; t < 2; ++t)
        accB[t] = __builtin_amdgcn_mfma_f32_16x16x32_bf16(af[t][kk], bfr[kk], accB[t], 0, 0, 0);
    __builtin_amdgcn_s_setprio(0);

    float cyv[2][4], ynv[2][4], t1v[2][4], t1s[2][4];
#pragma unroll
    for (int t = 0; t < 2; ++t) {
      f32x4 acc = accA[t] + accB[t];
      float xv[4];
      xv[0] = bf2f((short)xq[t].x);
      xv[1] = bf2f((short)(xq[t].x >> 16));
      xv[2] = bf2f((short)xq[t].y);
      xv[3] = bf2f((short)(xq[t].y >> 16));
#pragma unroll
      for (int r = 0; r < 4; ++r) {
        cyv[t][r] = relu_(acc[r]);
        ynv[t][r] = xv[r] + cyv[t][r];
        t1v[t][r] = relu_(ynv[t][r] * inv[t][r] + addv[t][r]);
      }
    }
#pragma unroll
    for (int t = 0; t < 2; ++t)
#pragma unroll
      for (int r = 0; r < 4; ++r) t1s[t][r] = dpp_xor8(t1v[t][r]);
#pragma unroll
    for (int t = 0; t < 2; ++t) {
      float sel[4], tt2[4];
#pragma unroll
      for (int r = 0; r < 4; ++r) {
        float znew = t1s[t][r] + cyv[t][r];
        tt2[r] = relu_(znew * inv[t][r] + addv[t][r]);
        sel[r] = isz ? znew : ynv[t][r];
      }
      *(uint2*)(smem + nxt * 8192 + woff[t]) =
          make_uint2(cvtpk(sel[0], sel[1]), cvtpk(sel[2], sel[3]));
      if (isz)
        *(uint2*)(xs + ((xb[t] + k * 4096) ^ (((2 * nr + k) & 15) << 3))) =
            make_uint2(cvtpk(tt2[0], tt2[1]), cvtpk(tt2[2], tt2[3]));
    }

    if (k < 24 && !isz) {
      const int Sn = ((2 * nr + k + 1) & 15) << 3;
#pragma unroll
      for (int t = 0; t < 2; ++t)
        xq[t] = *(const uint2*)(xs + ((xb[t] + (k + 1) * 4096) ^ Sn));
    }
    __syncthreads();
  }

  {
    const int kb = (wave == 0) ? 0 : 4 + 3 * (wave - 1);
    const int ke = kb + (wave ? 3 : 4);
    float acc[8][3];
#pragma unroll
    for (int rn = 0; rn < 8; ++rn)
#pragma unroll
      for (int dh = 0; dh < 3; ++dh) acc[rn][dh] = 0.f;

#pragma unroll 1
    for (int k = kb; k < ke; ++k) {
      f32x4 a0 = *(const f32x4*)(A + (0 * 25 + 24 - k) * 256 + 4 * lane);
      f32x4 a1 = *(const f32x4*)(A + (1 * 25 + 24 - k) * 256 + 4 * lane);
      f32x4 a2 = *(const f32x4*)(A + (2 * 25 + 24 - k) * 256 + 4 * lane);
#pragma unroll
      for (int rn = 0; rn < 8; ++rn) {
        int Sp = ((2 * rn + k) & 15) << 3;
        uint2 q = *(const uint2*)(xs + ((k * 4096 + rn * 512 + 8 * lane) ^ Sp));
        float v0 = bf2f((short)q.x), v1 = bf2f((short)(q.x >> 16));
        float v2 = bf2f((short)q.y), v3 = bf2f((short)(q.y >> 16));
#pragma unroll
        for (int dh = 0; dh < 3; ++dh) {
          f32x4 a = dh == 0 ? a0 : (dh == 1 ? a1 : a2);
          float s = acc[rn][dh];
          s = fmaf(a[0], v0, s);
          s = fmaf(a[1], v1, s);
          s = fmaf(a[2], v2, s);
          s = fmaf(a[3], v3, s);
          acc[rn][dh] = s;
        }
      }
    }
#pragma unroll
    for (int rn = 0; rn < 8; ++rn)
#pragma unroll
      for (int dh = 0; dh < 3; ++dh) {
        float v = acc[rn][dh];
        v += __shfl_xor(v, 1);
        v += __shfl_xor(v, 2);
        v += __shfl_xor(v, 4);
        v += __shfl_xor(v, 8);
        v += __shfl_xor(v, 16);
        v += __shfl_xor(v, 32);
        if (lane == 0) red[wave][rn][dh] = v;
      }
  }
  __syncthreads();
  if (tid < 24) {
    int nn = tid / 3, dh = tid % 3;
    float v = 0.f;
#pragma unroll
    for (int ww = 0; ww < 8; ++ww) v += red[ww][nn][dh];
    S[(size_t)(col0 + nn) * 3 + dh] = v;
  }
}

// ---- PROBE: staging only, A/B of the two variants ----
template <int VAR>
__global__ __launch_bounds__(512, 1) void p_stage(
    const float* __restrict__ X, float* __restrict__ scrap)
{
  __shared__ short xslab[25 * 8 * 256];
  const int tid = threadIdx.x;
  const int wave = tid >> 6;
  const int lane = tid & 63;
  const int col0 = blockIdx.x * NC;
  const int b = col0 >> 8, h0 = col0 & 255;
  char* xs = (char*)xslab;

  stage_slab<VAR>(X, xs, b, h0, wave * 32, lane);
  __syncthreads();
  // keep-alive: consume staged data
  float v = bf2f(*(const short*)(xs + 2 * tid)) + bf2f(*(const short*)(xs + 51200 + 2 * tid));
  scrap[(size_t)blockIdx.x * 512 + tid] = v;
}

// ---- merged tail: conv-h fold + 3 upsamples + sigmoid ----
__global__ __launch_bounds__(256) void k34_final(
    const float* __restrict__ S, float* __restrict__ out)
{
  int idx = blockIdx.x * blockDim.x + threadIdx.x;
  if (idx >= 8 * 2048) return;
  int b = idx >> 11, H = idx & 2047;

  auto Pf = [&](int h) -> float {
    float acc = 0.f;
#pragma unroll
    for (int dh = 0; dh < 3; ++dh) {
      int hh = h + dh - 1;
      if (hh < 0 || hh >= 512) continue;
      float pos = hh * (255.0f / 511.0f);
      int i0 = (int)floorf(pos);
      int i1 = min(i0 + 1, 255);
      float t = pos - (float)i0;
      acc += (1.f - t) * S[(size_t)(b * 256 + i0) * 3 + dh]
           + t * S[(size_t)(b * 256 + i1) * 3 + dh];
    }
    return acc;
  };

  float pos3 = H * (1023.0f / 2047.0f);
  int i3 = (int)floorf(pos3);
  int i3b = min(i3 + 1, 1023);
  float t3 = pos3 - (float)i3;

  float v[2];
#pragma unroll
  for (int q = 0; q < 2; ++q) {
    int i = q ? i3b : i3;
    float pos2 = i * (511.0f / 1023.0f);
    int i2 = (int)floorf(pos2);
    int i2b = min(i2 + 1, 511);
    float t2 = pos2 - (float)i2;
    v[q] = (1.f - t2) * Pf(i2) + t2 * Pf(i2b);
  }
  float val = (1.f - t3) * v[0] + t3 * v[1];
  out[idx] = 1.f / (1.f + expf(-val));
}

extern "C" void kernel_launch(void* const* d_in, const int* in_sizes, int n_in,
                              void* d_out, int out_size, void* d_ws, size_t ws_size,
                              hipStream_t stream) {
  (void)in_sizes; (void)n_in; (void)out_size; (void)ws_size;
  const float* p2r    = (const float*)d_in[0];
  const float* Wmsg   = (const float*)d_in[1];
  const float* gamma  = (const float*)d_in[2];
  const float* beta   = (const float*)d_in[3];
  const float* mean   = (const float*)d_in[4];
  const float* var    = (const float*)d_in[5];
  const float* Wup2   = (const float*)d_in[6];
  const float* Wconv  = (const float*)d_in[7];
  const float* Wconv2 = (const float*)d_in[8];
  float* out = (float*)d_out;

  float* ws = (float*)d_ws;
  size_t off = 0;
  short* WcA = (short*)(ws + off); off += 32768;   // 65536 bf16
  float* Abuf = ws + off; off += 19200;
  float* bnp = ws + off;  off += 512;
  float* S = ws + off;    off += 6144;
  float* scrap = ws + off; off += 131072;          // probe keep-alive

  k0_precompute<<<256, 64, 0, stream>>>(Wmsg, gamma, beta, mean, var, Wup2,
                                        Wconv, Wconv2, WcA, Abuf, bnp);
  k2_fused<<<256, 512, 0, stream>>>(p2r, (const short*)WcA, Abuf, bnp, S);
  k34_final<<<64, 256, 0, stream>>>(S, out);
  // staging A/B probes (timing instruments; write only scrap)
  p_stage<0><<<256, 512, 0, stream>>>(p2r, scrap);
  p_stage<1><<<256, 512, 0, stream>>>(p2r, scrap);
}

// Round 13
// 52.163 us; speedup vs baseline: 3.8860x; 1.3797x over previous
//
#include <hip/hip_runtime.h>
#include <math.h>

// Algebraic refactor (verified rounds 1-12, absmax <= 0.0039):
//  y[0]=x[...,0]; y[k]=x[...,k]+relu(Wc@y[k-1])
//  z[0]=f(y[0]);  z[k]=f(y[k])+relu(Wc@z[k-1]),  f(v)=relu(v*inv+add)
//  S[col][dh] = sum_{o,k} A[dh][24-k][o] * t2[k][o][col],  t2[k]=f(z[k])
//  tail: lerp chains + sigmoid (k34)
// Round 13: CLEANUP. Probes stripped (were +19us of dur_us). Pipeline =
//  best-known config: k0 precompute, k2_fused (8 waves x 32ch, NC=8,
//  batched staging, setprio, DPP, prefetch-before-barrier, batched
//  epilogue, fused post-phase), k34 merged tail.
// Measured decomposition (R11/R12 probes): staging ~9us (= HBM roofline,
//  52MB at ~5.8TB/s), serial loop ~23us (~2300cyc/step equilibrium,
//  invariant across 7 structural variants), post ~2us, prologue ~8us.

#define NC 8

typedef __attribute__((ext_vector_type(8))) short bf16x8;
typedef __attribute__((ext_vector_type(4))) float f32x4;

__device__ __forceinline__ float relu_(float v) { return fmaxf(v, 0.f); }

__device__ __forceinline__ short f2bf(float f) {
  union { float f; unsigned u; } v; v.f = f;
  unsigned r = (v.u + 0x7fffu + ((v.u >> 16) & 1u)) >> 16;
  return (short)r;
}
__device__ __forceinline__ float bf2f(short s) {
  union { unsigned u; float f; } v;
  v.u = ((unsigned)(unsigned short)s) << 16;
  return v.f;
}
__device__ __forceinline__ unsigned cvtpk(float lo, float hi) {
  unsigned r;
  asm("v_cvt_pk_bf16_f32 %0, %1, %2" : "=v"(r) : "v"(lo), "v"(hi));
  return r;
}
// lane^8 exchange within each 16-lane row: DPP row_ror:8 (VALU pipe, no DS)
__device__ __forceinline__ float dpp_xor8(float v) {
  int r = __builtin_amdgcn_update_dpp(0, __float_as_int(v), 0x128, 0xf, 0xf, true);
  return __int_as_float(r);
}

// batched staging: issue 16 loads back-to-back (MLP 16), then pack+write
__device__ __forceinline__ void stage_slab(
    const float* __restrict__ X, char* xs, int b, int h0, int obase, int lane)
{
  if (lane >= 50) return;
  int base_[4], sx_[4];
#pragma unroll
  for (int e = 0; e < 4; ++e) {
    int f = 4 * lane + e;
    int rn = f / 25, w = f - rn * 25;
    base_[e] = w * 4096 + rn * 512;
    sx_[e] = ((2 * rn + w) & 15) << 3;
  }
  const float* src0 = X + (size_t)(b * 256 + obase) * 6400 + h0 * 25 + 4 * lane;
#pragma unroll
  for (int hb = 0; hb < 2; ++hb) {
    float4 va[16];
#pragma unroll
    for (int j = 0; j < 16; ++j)
      va[j] = *(const float4*)(src0 + (size_t)(hb * 16 + j) * 6400);
#pragma unroll
    for (int i = 0; i < 8; ++i) {
      unsigned p[4] = {cvtpk(va[2 * i].x, va[2 * i + 1].x),
                       cvtpk(va[2 * i].y, va[2 * i + 1].y),
                       cvtpk(va[2 * i].z, va[2 * i + 1].z),
                       cvtpk(va[2 * i].w, va[2 * i + 1].w)};
      const int cb = 2 * obase + 4 * (hb * 8 + i);
#pragma unroll
      for (int e = 0; e < 4; ++e)
        *(unsigned*)(xs + base_[e] + (cb ^ sx_[e])) = p[e];
    }
  }
}

__global__ __launch_bounds__(64) void k0_precompute(
    const float* __restrict__ Wmsg, const float* __restrict__ gamma,
    const float* __restrict__ beta, const float* __restrict__ mean,
    const float* __restrict__ var, const float* __restrict__ Wup2,
    const float* __restrict__ Wconv, const float* __restrict__ Wconv2,
    short* __restrict__ WcA, float* __restrict__ A, float* __restrict__ bnp)
{
  const int c = blockIdx.x;      // 0..255
  const int lane = threadIdx.x;  // 0..63

  for (int o = lane; o < 256; o += 64)
    WcA[o * 256 + c] = f2bf(Wmsg[(o * 256 + c) * 9 + 4]);

  const int gtid = c * 64 + lane;
  if (gtid < 256) {
    float inv = gamma[gtid] / sqrtf(var[gtid] + 1e-5f);
    bnp[gtid] = inv;
    bnp[256 + gtid] = beta[gtid] - mean[gtid] * inv;
  }

  float wacc[9];
#pragma unroll
  for (int q = 0; q < 9; ++q) wacc[q] = 0.f;
  for (int o = lane; o < 256; o += 64) {
    float cw = Wconv[o];
    const float* wp = Wup2 + (size_t)(o * 256 + c) * 9;
#pragma unroll
    for (int q = 0; q < 9; ++q) wacc[q] += cw * wp[q];
  }
#pragma unroll
  for (int q = 0; q < 9; ++q) {
    float v = wacc[q];
    v += __shfl_xor(v, 32, 64);
    v += __shfl_xor(v, 16, 64);
    v += __shfl_xor(v, 8, 64);
    v += __shfl_xor(v, 4, 64);
    v += __shfl_xor(v, 2, 64);
    v += __shfl_xor(v, 1, 64);
    wacc[q] = v;
  }
  if (lane == 0) {
    for (int dh = 0; dh < 3; ++dh)
      for (int j = 0; j < 25; ++j) {
        float a = 0.f;
        for (int dw = 0; dw < 3; ++dw) {
          int w = j + 1 - dw;
          if (w >= 0 && w < 25) a += wacc[dh * 3 + dw] * Wconv2[w];
        }
        A[(dh * 25 + j) * 256 + c] = a;
      }
  }
}

// ---- fused MFMA dual-recurrence kernel (8 waves x 32 channels, NC=8) ----
// lane n=lane&15: n<8 -> y col n, n>=8 -> z col n-8 (8 consecutive h).
// xslab: [w][rn][c] bf16, addr = (w*4096+rn*512+2c) ^ (((2rn+w)&15)<<3).
// Plane k is overwritten with t2[k] by z-lanes after step k consumes it.
__global__ __launch_bounds__(512, 1) void k2_fused(
    const float* __restrict__ X,     // p2_r [b][c][h][w]
    const short* __restrict__ WcA,   // bf16 [o][c]
    const float* __restrict__ A,     // [(dh*25+w)*256+c]
    const float* __restrict__ bnp,   // inv[256], add[256]
    float* __restrict__ S)           // [col*3+dh]
{
  __shared__ short xslab[25 * 8 * 256];  // 102400B
  __shared__ short yz[2][16 * 256];      // state, swizzled (2x8192B)
  __shared__ float red[8][8][3];
  const int tid = threadIdx.x;
  const int wave = tid >> 6;
  const int lane = tid & 63;
  const int n = lane & 15;
  const int nr = n & 7;
  const int g = lane >> 4;
  const bool isz = (n >= 8);
  const int col0 = blockIdx.x * NC;      // col = b*256+h
  const int b = col0 >> 8, h0 = col0 & 255;
  const int obase = wave * 32;
  char* xs = (char*)xslab;
  char* smem = (char*)yz;

  stage_slab(X, xs, b, h0, obase, lane);

  f32x4 inv[2], addv[2];
#pragma unroll
  for (int t = 0; t < 2; ++t) {
    inv[t] = *(const f32x4*)(bnp + obase + t * 16 + g * 4);
    addv[t] = *(const f32x4*)(bnp + 256 + obase + t * 16 + g * 4);
  }

  bf16x8 af[2][8];
#pragma unroll
  for (int t = 0; t < 2; ++t)
#pragma unroll
    for (int kk = 0; kk < 8; ++kk)
      af[t][kk] = *(const bf16x8*)(WcA + (obase + t * 16 + n) * 256 + kk * 32 + g * 8);

  const int swz = nr << 4;
  int woff[2], xb[2], roff[8];
#pragma unroll
  for (int t = 0; t < 2; ++t) {
    woff[t] = n * 512 + (((obase + t * 16 + g * 4) * 2) ^ swz);
    xb[t] = nr * 512 + 2 * (obase + t * 16 + g * 4);
  }
#pragma unroll
  for (int kk = 0; kk < 8; ++kk)
    roff[kk] = n * 512 + ((kk * 64 + g * 16) ^ swz);

  __syncthreads();  // slab ready

  {
    const int S0 = ((2 * nr) & 15) << 3;
#pragma unroll
    for (int t = 0; t < 2; ++t) {
      uint2 xq0 = *(const uint2*)(xs + (xb[t] ^ S0));
      if (!isz) {
        *(uint2*)(smem + woff[t]) = xq0;  // y0 = x0: raw bf16 copy
      } else {
        float zr[4], t2r[4];
        float xv[4] = {bf2f((short)xq0.x), bf2f((short)(xq0.x >> 16)),
                       bf2f((short)xq0.y), bf2f((short)(xq0.y >> 16))};
#pragma unroll
        for (int r = 0; r < 4; ++r) {
          zr[r] = relu_(xv[r] * inv[t][r] + addv[t][r]);
          t2r[r] = relu_(zr[r] * inv[t][r] + addv[t][r]);
        }
        *(uint2*)(smem + woff[t]) = make_uint2(cvtpk(zr[0], zr[1]), cvtpk(zr[2], zr[3]));
        *(uint2*)(xs + (xb[t] ^ S0)) =
            make_uint2(cvtpk(t2r[0], t2r[1]), cvtpk(t2r[2], t2r[3]));
      }
    }
  }

  // prefetch x for k=1 (before the barrier: plane 1 untouched until step 1)
  uint2 xq[2];
  xq[0] = make_uint2(0u, 0u);
  xq[1] = make_uint2(0u, 0u);
  if (!isz) {
    const int S1 = ((2 * nr + 1) & 15) << 3;
#pragma unroll
    for (int t = 0; t < 2; ++t)
      xq[t] = *(const uint2*)(xs + ((xb[t] + 4096) ^ S1));
  }
  __syncthreads();

  // ---- serial steps k = 1..24 (LDS-only) ----
#pragma unroll 1
  for (int k = 1; k < 25; ++k) {
    const int cur = (k - 1) & 1, nxt = k & 1;

    bf16x8 bfr[8];
#pragma unroll
    for (int kk = 0; kk < 8; ++kk)
      bfr[kk] = *(const bf16x8*)(smem + cur * 8192 + roff[kk]);

    f32x4 accA[2], accB[2];
#pragma unroll
    for (int t = 0; t < 2; ++t) {
      accA[t] = (f32x4){0.f, 0.f, 0.f, 0.f};
      accB[t] = (f32x4){0.f, 0.f, 0.f, 0.f};
    }
    __builtin_amdgcn_s_setprio(1);
#pragma unroll
    for (int kk = 0; kk < 4; ++kk)
#pragma unroll
      for (int t = 0; t < 2; ++t)
        accA[t] = __builtin_amdgcn_mfma_f32_16x16x32_bf16(af[t][kk], bfr[kk], accA[t], 0, 0, 0);
#pragma unroll
    for (int kk = 4; kk < 8; ++kk)
#pragma unroll
      for (int t = 0; t < 2; ++t)
        accB[t] = __builtin_amdgcn_mfma_f32_16x16x32_bf16(af[t][kk], bfr[kk], accB[t], 0, 0, 0);
    __builtin_amdgcn_s_setprio(0);

    // batched epilogue: phase 1 (y-side), phase 2 (16 DPPs), phase 3 (z-side)
    float cyv[2][4], ynv[2][4], t1v[2][4], t1s[2][4];
#pragma unroll
    for (int t = 0; t < 2; ++t) {
      f32x4 acc = accA[t] + accB[t];
      float xv[4];
      xv[0] = bf2f((short)xq[t].x);
      xv[1] = bf2f((short)(xq[t].x >> 16));
      xv[2] = bf2f((short)xq[t].y);
      xv[3] = bf2f((short)(xq[t].y >> 16));
#pragma unroll
      for (int r = 0; r < 4; ++r) {
        cyv[t][r] = relu_(acc[r]);
        ynv[t][r] = xv[r] + cyv[t][r];                            // y-lanes
        t1v[t][r] = relu_(ynv[t][r] * inv[t][r] + addv[t][r]);    // y-lanes
      }
    }
#pragma unroll
    for (int t = 0; t < 2; ++t)
#pragma unroll
      for (int r = 0; r < 4; ++r) t1s[t][r] = dpp_xor8(t1v[t][r]);
#pragma unroll
    for (int t = 0; t < 2; ++t) {
      float sel[4], tt2[4];
#pragma unroll
      for (int r = 0; r < 4; ++r) {
        float znew = t1s[t][r] + cyv[t][r];                       // z-lanes
        tt2[r] = relu_(znew * inv[t][r] + addv[t][r]);
        sel[r] = isz ? znew : ynv[t][r];
      }
      *(uint2*)(smem + nxt * 8192 + woff[t]) =
          make_uint2(cvtpk(sel[0], sel[1]), cvtpk(sel[2], sel[3]));
      if (isz)
        *(uint2*)(xs + ((xb[t] + k * 4096) ^ (((2 * nr + k) & 15) << 3))) =
            make_uint2(cvtpk(tt2[0], tt2[1]), cvtpk(tt2[2], tt2[3]));
    }

    // prefetch x for k+1 BEFORE the barrier (plane k+1 untouched until k+1)
    if (k < 24 && !isz) {
      const int Sn = ((2 * nr + k + 1) & 15) << 3;
#pragma unroll
      for (int t = 0; t < 2; ++t)
        xq[t] = *(const uint2*)(xs + ((xb[t] + (k + 1) * 4096) ^ Sn));
    }
    __syncthreads();
  }

  // ---- parallel post-phase: S[col][dh] = sum_{c,k} A[dh][24-k][c]*t2[k][col][c]
  {
    const int kb = (wave == 0) ? 0 : 4 + 3 * (wave - 1);
    const int ke = kb + (wave ? 3 : 4);
    float acc[8][3];
#pragma unroll
    for (int rn = 0; rn < 8; ++rn)
#pragma unroll
      for (int dh = 0; dh < 3; ++dh) acc[rn][dh] = 0.f;

#pragma unroll 1
    for (int k = kb; k < ke; ++k) {
      f32x4 a0 = *(const f32x4*)(A + (0 * 25 + 24 - k) * 256 + 4 * lane);
      f32x4 a1 = *(const f32x4*)(A + (1 * 25 + 24 - k) * 256 + 4 * lane);
      f32x4 a2 = *(const f32x4*)(A + (2 * 25 + 24 - k) * 256 + 4 * lane);
#pragma unroll
      for (int rn = 0; rn < 8; ++rn) {
        int Sp = ((2 * rn + k) & 15) << 3;
        uint2 q = *(const uint2*)(xs + ((k * 4096 + rn * 512 + 8 * lane) ^ Sp));
        float v0 = bf2f((short)q.x), v1 = bf2f((short)(q.x >> 16));
        float v2 = bf2f((short)q.y), v3 = bf2f((short)(q.y >> 16));
#pragma unroll
        for (int dh = 0; dh < 3; ++dh) {
          f32x4 a = dh == 0 ? a0 : (dh == 1 ? a1 : a2);
          float s = acc[rn][dh];
          s = fmaf(a[0], v0, s);
          s = fmaf(a[1], v1, s);
          s = fmaf(a[2], v2, s);
          s = fmaf(a[3], v3, s);
          acc[rn][dh] = s;
        }
      }
    }
#pragma unroll
    for (int rn = 0; rn < 8; ++rn)
#pragma unroll
      for (int dh = 0; dh < 3; ++dh) {
        float v = acc[rn][dh];
        v += __shfl_xor(v, 1);
        v += __shfl_xor(v, 2);
        v += __shfl_xor(v, 4);
        v += __shfl_xor(v, 8);
        v += __shfl_xor(v, 16);
        v += __shfl_xor(v, 32);
        if (lane == 0) red[wave][rn][dh] = v;
      }
  }
  __syncthreads();
  if (tid < 24) {
    int nn = tid / 3, dh = tid % 3;
    float v = 0.f;
#pragma unroll
    for (int ww = 0; ww < 8; ++ww) v += red[ww][nn][dh];
    S[(size_t)(col0 + nn) * 3 + dh] = v;
  }
}

// ---- merged tail: conv-h fold + 3 upsamples + sigmoid ----
__global__ __launch_bounds__(256) void k34_final(
    const float* __restrict__ S, float* __restrict__ out)
{
  int idx = blockIdx.x * blockDim.x + threadIdx.x;
  if (idx >= 8 * 2048) return;
  int b = idx >> 11, H = idx & 2047;

  auto Pf = [&](int h) -> float {
    float acc = 0.f;
#pragma unroll
    for (int dh = 0; dh < 3; ++dh) {
      int hh = h + dh - 1;
      if (hh < 0 || hh >= 512) continue;
      float pos = hh * (255.0f / 511.0f);
      int i0 = (int)floorf(pos);
      int i1 = min(i0 + 1, 255);
      float t = pos - (float)i0;
      acc += (1.f - t) * S[(size_t)(b * 256 + i0) * 3 + dh]
           + t * S[(size_t)(b * 256 + i1) * 3 + dh];
    }
    return acc;
  };

  float pos3 = H * (1023.0f / 2047.0f);
  int i3 = (int)floorf(pos3);
  int i3b = min(i3 + 1, 1023);
  float t3 = pos3 - (float)i3;

  float v[2];
#pragma unroll
  for (int q = 0; q < 2; ++q) {
    int i = q ? i3b : i3;
    float pos2 = i * (511.0f / 1023.0f);
    int i2 = (int)floorf(pos2);
    int i2b = min(i2 + 1, 511);
    float t2 = pos2 - (float)i2;
    v[q] = (1.f - t2) * Pf(i2) + t2 * Pf(i2b);
  }
  float val = (1.f - t3) * v[0] + t3 * v[1];
  out[idx] = 1.f / (1.f + expf(-val));
}

extern "C" void kernel_launch(void* const* d_in, const int* in_sizes, int n_in,
                              void* d_out, int out_size, void* d_ws, size_t ws_size,
                              hipStream_t stream) {
  (void)in_sizes; (void)n_in; (void)out_size; (void)ws_size;
  const float* p2r    = (const float*)d_in[0];
  const float* Wmsg   = (const float*)d_in[1];
  const float* gamma  = (const float*)d_in[2];
  const float* beta   = (const float*)d_in[3];
  const float* mean   = (const float*)d_in[4];
  const float* var    = (const float*)d_in[5];
  const float* Wup2   = (const float*)d_in[6];
  const float* Wconv  = (const float*)d_in[7];
  const float* Wconv2 = (const float*)d_in[8];
  float* out = (float*)d_out;

  float* ws = (float*)d_ws;
  size_t off = 0;
  short* WcA = (short*)(ws + off); off += 32768;  // 65536 bf16
  float* Abuf = ws + off; off += 19200;
  float* bnp = ws + off;  off += 512;
  float* S = ws + off;    off += 6144;

  k0_precompute<<<256, 64, 0, stream>>>(Wmsg, gamma, beta, mean, var, Wup2,
                                        Wconv, Wconv2, WcA, Abuf, bnp);
  k2_fused<<<256, 512, 0, stream>>>(p2r, (const short*)WcA, Abuf, bnp, S);
  k34_final<<<64, 256, 0, stream>>>(S, out);
}